// Round 5
// baseline (258.174 us; speedup 1.0000x reference)
//
#include <hip/hip_runtime.h>
#include <hip/hip_bf16.h>
#include <math.h>

#define N_NODES 50000
#define N_EDGES 800000
#define N_FEAT 128
#define HIDDEN 16
#define N_CLASSES 16

#define NBUCK 782          // ceil(50000 / 64) buckets of 64 dst nodes
#define PB_NB 196          // partition blocks
#define PB_E  4096         // edges per partition block (196*4096 >= 800000)

// ---------------------------------------------------------------------------
// K1: layer-1 node transform. h0 = x@w1[0], h1 = x@w1[1], p1 = x@root1 + b1.
// AB[n][32] stores (h0[o], h1[o]) interleaved at [n*32 + 2o] so the gather
// reads one float2 per lane (128B contiguous per 16-lane edge group).
// 4 nodes per thread: W LDS reads amortized (R3 was LDS-pipe-bound).
// ---------------------------------------------------------------------------
__global__ __launch_bounds__(256) void k_node1(
    const float* __restrict__ x, const float* __restrict__ w1,
    const float* __restrict__ root1, const float* __restrict__ b1,
    float* __restrict__ AB, float* __restrict__ C)
{
    __shared__ float W[48 * 132];
    for (int t = threadIdx.x; t < 48 * 128; t += 256) {
        int o = t >> 7;
        int i = t & 127;
        float v;
        if (o < 16)       v = w1[i * 16 + o];
        else if (o < 32)  v = w1[2048 + i * 16 + (o - 16)];
        else              v = root1[i * 16 + (o - 32)];
        W[o * 132 + i] = v;
    }
    __syncthreads();

    int o = threadIdx.x & 15;
    int g = threadIdx.x >> 4;
    int nbase = blockIdx.x * 64 + g * 4;

    int n0 = min(nbase + 0, N_NODES - 1);
    int n1 = min(nbase + 1, N_NODES - 1);
    int n2 = min(nbase + 2, N_NODES - 1);
    int n3 = min(nbase + 3, N_NODES - 1);

    const float4* x0 = (const float4*)(x + (size_t)n0 * N_FEAT);
    const float4* x1 = (const float4*)(x + (size_t)n1 * N_FEAT);
    const float4* x2 = (const float4*)(x + (size_t)n2 * N_FEAT);
    const float4* x3 = (const float4*)(x + (size_t)n3 * N_FEAT);

    float acc[4][3];
#pragma unroll
    for (int j = 0; j < 4; ++j)
#pragma unroll
        for (int k = 0; k < 3; ++k) acc[j][k] = 0.f;

#pragma unroll 4
    for (int i4 = 0; i4 < 32; ++i4) {
        float4 wa = *(const float4*)&W[o * 132 + 4 * i4];
        float4 wb = *(const float4*)&W[(o + 16) * 132 + 4 * i4];
        float4 wr = *(const float4*)&W[(o + 32) * 132 + 4 * i4];
        float4 xv[4];
        xv[0] = x0[i4]; xv[1] = x1[i4]; xv[2] = x2[i4]; xv[3] = x3[i4];
#pragma unroll
        for (int j = 0; j < 4; ++j) {
            acc[j][0] += xv[j].x * wa.x + xv[j].y * wa.y + xv[j].z * wa.z + xv[j].w * wa.w;
            acc[j][1] += xv[j].x * wb.x + xv[j].y * wb.y + xv[j].z * wb.z + xv[j].w * wb.w;
            acc[j][2] += xv[j].x * wr.x + xv[j].y * wr.y + xv[j].z * wr.z + xv[j].w * wr.w;
        }
    }

    float bo = b1[o];
#pragma unroll
    for (int j = 0; j < 4; ++j) {
        int n = nbase + j;
        if (n < N_NODES) {
            *(float2*)&AB[(size_t)n * 32 + 2 * o] = make_float2(acc[j][0], acc[j][1]);
            C[(size_t)n * 16 + o] = acc[j][2] + bo;
        }
    }
}

// ---------------------------------------------------------------------------
// Bucket partition: hist per (bucket, block) in LDS, scan, then scatter with
// per-block-contiguous runs per bucket (writes mostly line-local).
// ---------------------------------------------------------------------------
__global__ __launch_bounds__(256) void k_histA(
    const int* __restrict__ dst, int* __restrict__ blk)
{
    __shared__ int cnt[NBUCK];
    for (int i = threadIdx.x; i < NBUCK; i += 256) cnt[i] = 0;
    __syncthreads();
    int base = blockIdx.x * PB_E;
#pragma unroll
    for (int k = 0; k < PB_E / 256; ++k) {
        int e = base + k * 256 + threadIdx.x;
        if (e < N_EDGES) atomicAdd(&cnt[dst[e] >> 6], 1);
    }
    __syncthreads();
    for (int i = threadIdx.x; i < NBUCK; i += 256)
        blk[i * PB_NB + blockIdx.x] = cnt[i];
}

// Per-bucket exclusive scan over the 196 block counts (in-place) + bucket total.
__global__ __launch_bounds__(256) void k_scanblk(
    int* __restrict__ blk, int* __restrict__ bucktot)
{
    __shared__ int s[256];
    int b = blockIdx.x, t = threadIdx.x;
    int v = (t < PB_NB) ? blk[b * PB_NB + t] : 0;
    s[t] = v;
    __syncthreads();
#pragma unroll
    for (int off = 1; off < 256; off <<= 1) {
        int w = (t >= off) ? s[t - off] : 0;
        __syncthreads();
        s[t] += w;
        __syncthreads();
    }
    if (t < PB_NB) blk[b * PB_NB + t] = s[t] - v;
    if (t == PB_NB - 1) bucktot[b] = s[t];
}

// Exclusive scan of the 782 bucket totals.
__global__ __launch_bounds__(1024) void k_scanbase(
    const int* __restrict__ bucktot, int* __restrict__ buckbase)
{
    __shared__ int s[1024];
    int t = threadIdx.x;
    int v = (t < NBUCK) ? bucktot[t] : 0;
    s[t] = v;
    __syncthreads();
#pragma unroll
    for (int off = 1; off < 1024; off <<= 1) {
        int w = (t >= off) ? s[t - off] : 0;
        __syncthreads();
        s[t] += w;
        __syncthreads();
    }
    if (t < NBUCK) buckbase[t] = s[t] - v;
    if (t == 0) buckbase[NBUCK] = N_EDGES;
}

// Scatter edges to bucket-grouped storage. Payload: {src | dst_local<<16, u}.
__global__ __launch_bounds__(256) void k_partition(
    const int* __restrict__ src, const int* __restrict__ dst,
    const float* __restrict__ u, const int* __restrict__ buckbase,
    const int* __restrict__ blk, int2* __restrict__ epb)
{
    __shared__ int rank[NBUCK];
    __shared__ int base_s[NBUCK];
    for (int i = threadIdx.x; i < NBUCK; i += 256) {
        rank[i] = 0;
        base_s[i] = buckbase[i] + blk[i * PB_NB + blockIdx.x];
    }
    __syncthreads();
    int ebase = blockIdx.x * PB_E;
#pragma unroll
    for (int k = 0; k < PB_E / 256; ++k) {
        int e = ebase + k * 256 + threadIdx.x;
        if (e < N_EDGES) {
            int d = dst[e];
            int b = d >> 6;
            int pos = base_s[b] + atomicAdd(&rank[b], 1);
            epb[pos] = make_int2((src[e] & 0xFFFF) | ((d & 63) << 16),
                                 __float_as_int(u[e]));
        }
    }
}

// ---------------------------------------------------------------------------
// Bucket-local gather-mean: one block per bucket of 64 dst nodes.
// 16 lanes per edge; messages accumulated in LDS (ds f32 atomics); deg in
// LDS; mean + coalesced AGG write. No global atomics, no per-node sort.
// ---------------------------------------------------------------------------
__global__ __launch_bounds__(256) void k_gatherB(
    const int* __restrict__ buckbase, const int2* __restrict__ epb,
    const float* __restrict__ AB, float* __restrict__ AGG)
{
    __shared__ float agg[64 * 16];
    __shared__ int degl[64];
    int b = blockIdx.x;
    int beg = buckbase[b], end = buckbase[b + 1];
    int o = threadIdx.x & 15, g = threadIdx.x >> 4;

    for (int i = threadIdx.x; i < 64 * 16; i += 256) agg[i] = 0.f;
    if (threadIdx.x < 64) degl[threadIdx.x] = 0;
    __syncthreads();

    int e = beg + g;
    for (; e + 16 < end; e += 32) {
        int2 p0 = epb[e];
        int2 p1 = epb[e + 16];
        int s0 = p0.x & 0xFFFF, dl0 = (p0.x >> 16) & 63;
        int s1 = p1.x & 0xFFFF, dl1 = (p1.x >> 16) & 63;
        float u0 = __int_as_float(p0.y);
        float u1 = __int_as_float(p1.y);
        float2 h0 = *(const float2*)&AB[(size_t)s0 * 32 + 2 * o];
        float2 h1 = *(const float2*)&AB[(size_t)s1 * 32 + 2 * o];
        atomicAdd(&agg[dl0 * 16 + o], (1.f - u0) * h0.x + u0 * h0.y);
        atomicAdd(&agg[dl1 * 16 + o], (1.f - u1) * h1.x + u1 * h1.y);
        if (o == 0) {
            atomicAdd(&degl[dl0], 1);
            atomicAdd(&degl[dl1], 1);
        }
    }
    if (e < end) {
        int2 p0 = epb[e];
        int s0 = p0.x & 0xFFFF, dl0 = (p0.x >> 16) & 63;
        float u0 = __int_as_float(p0.y);
        float2 h0 = *(const float2*)&AB[(size_t)s0 * 32 + 2 * o];
        atomicAdd(&agg[dl0 * 16 + o], (1.f - u0) * h0.x + u0 * h0.y);
        if (o == 0) atomicAdd(&degl[dl0], 1);
    }
    __syncthreads();

    int nbase = b << 6;
    for (int i = threadIdx.x; i < 64 * 16; i += 256) {
        int dl = i >> 4;
        int n = nbase + dl;
        if (n < N_NODES) {
            float dv = fmaxf((float)degl[dl], 1.f);
            AGG[(size_t)n * 16 + (i & 15)] = agg[i] / dv;
        }
    }
}

// ---------------------------------------------------------------------------
// K3: finish layer 1 (agg already meaned) + ELU + layer-2 node transform.
// AB rewritten with layer-2 (h0,h1) interleaved pairs; C becomes p2.
// ---------------------------------------------------------------------------
__global__ __launch_bounds__(256) void k_node2(
    const float* __restrict__ agg, float* __restrict__ C,
    const float* __restrict__ w2, const float* __restrict__ root2,
    const float* __restrict__ b2, float* __restrict__ AB)
{
    __shared__ float W2[16 * 48];
    __shared__ float hl[16][17];
    for (int t = threadIdx.x; t < 16 * 48; t += 256) {
        int j = t / 48, o = t % 48;
        float v;
        if (o < 16)       v = w2[j * 16 + o];
        else if (o < 32)  v = w2[256 + j * 16 + (o - 16)];
        else              v = root2[j * 16 + (o - 32)];
        W2[t] = v;
    }
    int nl = threadIdx.x >> 4;
    int o  = threadIdx.x & 15;
    int n  = blockIdx.x * 16 + nl;

    float pre = agg[(size_t)n * 16 + o] + C[(size_t)n * 16 + o];
    float h   = pre > 0.f ? pre : expm1f(pre);
    __syncthreads();
    hl[nl][o] = h;
    __syncthreads();

    float a = 0.f, b = 0.f, p = 0.f;
#pragma unroll
    for (int j = 0; j < 16; ++j) {
        float hv = hl[nl][j];
        a += hv * W2[j * 48 + o];
        b += hv * W2[j * 48 + 16 + o];
        p += hv * W2[j * 48 + 32 + o];
    }
    *(float2*)&AB[(size_t)n * 32 + 2 * o] = make_float2(a, b);
    C[(size_t)n * 16 + o] = p + b2[o];
}

// ---------------------------------------------------------------------------
// K5: log_softmax over 16 classes.
// ---------------------------------------------------------------------------
__global__ __launch_bounds__(256) void k_final(
    const float* __restrict__ agg, const float* __restrict__ C,
    float* __restrict__ out)
{
    int t = blockIdx.x * 256 + threadIdx.x;
    int n = t >> 4;
    int o = t & 15;
    float v = agg[(size_t)n * 16 + o] + C[(size_t)n * 16 + o];
    float m = v;
#pragma unroll
    for (int s = 1; s < 16; s <<= 1) m = fmaxf(m, __shfl_xor(m, s, 16));
    float ex = __expf(v - m);
    float ssum = ex;
#pragma unroll
    for (int s = 1; s < 16; s <<= 1) ssum += __shfl_xor(ssum, s, 16);
    out[(size_t)n * 16 + o] = v - m - __logf(ssum);
}

extern "C" void kernel_launch(void* const* d_in, const int* in_sizes, int n_in,
                              void* d_out, int out_size, void* d_ws, size_t ws_size,
                              hipStream_t stream) {
    const float* x     = (const float*)d_in[0];
    const int*   ei    = (const int*)d_in[1];
    const float* ea    = (const float*)d_in[2];
    const float* w1    = (const float*)d_in[3];
    const float* root1 = (const float*)d_in[4];
    const float* b1    = (const float*)d_in[5];
    const float* w2    = (const float*)d_in[6];
    const float* root2 = (const float*)d_in[7];
    const float* b2    = (const float*)d_in[8];
    float* out = (float*)d_out;

    char* ws = (char*)d_ws;
    float* AB       = (float*)ws;                                   // N*32
    float* C        = AB + (size_t)N_NODES * 32;                    // N*16
    float* AGG      = C + (size_t)N_NODES * 16;                     // N*16
    int2*  EPB      = (int2*)(AGG + (size_t)N_NODES * 16);          // E int2
    int*   BLK      = (int*)(EPB + N_EDGES);                        // NBUCK*PB_NB
    int*   BUCKTOT  = BLK + NBUCK * PB_NB;                          // NBUCK
    int*   BUCKBASE = BUCKTOT + NBUCK;                              // NBUCK+1

    const int* srcp = ei;
    const int* dstp = ei + N_EDGES;

    k_node1<<<782, 256, 0, stream>>>(x, w1, root1, b1, AB, C);
    k_histA<<<PB_NB, 256, 0, stream>>>(dstp, BLK);
    k_scanblk<<<NBUCK, 256, 0, stream>>>(BLK, BUCKTOT);
    k_scanbase<<<1, 1024, 0, stream>>>(BUCKTOT, BUCKBASE);
    k_partition<<<PB_NB, 256, 0, stream>>>(srcp, dstp, ea, BUCKBASE, BLK, EPB);

    k_gatherB<<<NBUCK, 256, 0, stream>>>(BUCKBASE, EPB, AB, AGG);
    k_node2<<<N_NODES / 16, 256, 0, stream>>>(AGG, C, w2, root2, b2, AB);
    k_gatherB<<<NBUCK, 256, 0, stream>>>(BUCKBASE, EPB, AB, AGG);
    k_final<<<N_NODES / 16, 256, 0, stream>>>(AGG, C, out);
}

// Round 6
// 124.057 us; speedup vs baseline: 2.0811x; 2.0811x over previous
//
#include <hip/hip_runtime.h>
#include <hip/hip_bf16.h>
#include <math.h>

#define N_NODES 50000
#define N_EDGES 800000
#define N_FEAT 128
#define HIDDEN 16
#define N_CLASSES 16

#define NBUCK 782          // ceil(50000 / 64) buckets of 64 dst nodes
#define PB_NB 196          // partition blocks
#define PB_E  4096         // edges per partition block (196*4096 >= 800000)
#define BCAP  1600         // max edges per bucket (mean 1023, sd ~32 -> 18 sigma)

// ---------------------------------------------------------------------------
// K1: layer-1 node transform. h0 = x@w1[0], h1 = x@w1[1], p1 = x@root1 + b1.
// AB[n][32] stores (h0[o], h1[o]) interleaved at [n*32 + 2o]: an 8-lane edge
// group in the gather reads float4 per lane (h0/h1 for 2 features) = 128B.
// ---------------------------------------------------------------------------
__global__ __launch_bounds__(256) void k_node1(
    const float* __restrict__ x, const float* __restrict__ w1,
    const float* __restrict__ root1, const float* __restrict__ b1,
    float* __restrict__ AB, float* __restrict__ C)
{
    __shared__ float W[48 * 132];
    for (int t = threadIdx.x; t < 48 * 128; t += 256) {
        int o = t >> 7;
        int i = t & 127;
        float v;
        if (o < 16)       v = w1[i * 16 + o];
        else if (o < 32)  v = w1[2048 + i * 16 + (o - 16)];
        else              v = root1[i * 16 + (o - 32)];
        W[o * 132 + i] = v;
    }
    __syncthreads();

    int o = threadIdx.x & 15;
    int g = threadIdx.x >> 4;
    int nbase = blockIdx.x * 64 + g * 4;

    int n0 = min(nbase + 0, N_NODES - 1);
    int n1 = min(nbase + 1, N_NODES - 1);
    int n2 = min(nbase + 2, N_NODES - 1);
    int n3 = min(nbase + 3, N_NODES - 1);

    const float4* x0 = (const float4*)(x + (size_t)n0 * N_FEAT);
    const float4* x1 = (const float4*)(x + (size_t)n1 * N_FEAT);
    const float4* x2 = (const float4*)(x + (size_t)n2 * N_FEAT);
    const float4* x3 = (const float4*)(x + (size_t)n3 * N_FEAT);

    float acc[4][3];
#pragma unroll
    for (int j = 0; j < 4; ++j)
#pragma unroll
        for (int k = 0; k < 3; ++k) acc[j][k] = 0.f;

#pragma unroll 4
    for (int i4 = 0; i4 < 32; ++i4) {
        float4 wa = *(const float4*)&W[o * 132 + 4 * i4];
        float4 wb = *(const float4*)&W[(o + 16) * 132 + 4 * i4];
        float4 wr = *(const float4*)&W[(o + 32) * 132 + 4 * i4];
        float4 xv[4];
        xv[0] = x0[i4]; xv[1] = x1[i4]; xv[2] = x2[i4]; xv[3] = x3[i4];
#pragma unroll
        for (int j = 0; j < 4; ++j) {
            acc[j][0] += xv[j].x * wa.x + xv[j].y * wa.y + xv[j].z * wa.z + xv[j].w * wa.w;
            acc[j][1] += xv[j].x * wb.x + xv[j].y * wb.y + xv[j].z * wb.z + xv[j].w * wb.w;
            acc[j][2] += xv[j].x * wr.x + xv[j].y * wr.y + xv[j].z * wr.z + xv[j].w * wr.w;
        }
    }

    float bo = b1[o];
#pragma unroll
    for (int j = 0; j < 4; ++j) {
        int n = nbase + j;
        if (n < N_NODES) {
            *(float2*)&AB[(size_t)n * 32 + 2 * o] = make_float2(acc[j][0], acc[j][1]);
            C[(size_t)n * 16 + o] = acc[j][2] + bo;
        }
    }
}

// ---------------------------------------------------------------------------
// Bucket partition (64-node buckets): per-(bucket,block) hist in LDS, two
// small scans, then scatter with per-block-contiguous runs per bucket.
// Payload: {src | dst_local<<16, u}.
// ---------------------------------------------------------------------------
__global__ __launch_bounds__(256) void k_histA(
    const int* __restrict__ dst, int* __restrict__ blk)
{
    __shared__ int cnt[NBUCK];
    for (int i = threadIdx.x; i < NBUCK; i += 256) cnt[i] = 0;
    __syncthreads();
    int base = blockIdx.x * PB_E;
#pragma unroll
    for (int k = 0; k < PB_E / 256; ++k) {
        int e = base + k * 256 + threadIdx.x;
        if (e < N_EDGES) atomicAdd(&cnt[dst[e] >> 6], 1);
    }
    __syncthreads();
    for (int i = threadIdx.x; i < NBUCK; i += 256)
        blk[i * PB_NB + blockIdx.x] = cnt[i];
}

__global__ __launch_bounds__(256) void k_scanblk(
    int* __restrict__ blk, int* __restrict__ bucktot)
{
    __shared__ int s[256];
    int b = blockIdx.x, t = threadIdx.x;
    int v = (t < PB_NB) ? blk[b * PB_NB + t] : 0;
    s[t] = v;
    __syncthreads();
#pragma unroll
    for (int off = 1; off < 256; off <<= 1) {
        int w = (t >= off) ? s[t - off] : 0;
        __syncthreads();
        s[t] += w;
        __syncthreads();
    }
    if (t < PB_NB) blk[b * PB_NB + t] = s[t] - v;
    if (t == PB_NB - 1) bucktot[b] = s[t];
}

__global__ __launch_bounds__(1024) void k_scanbase(
    const int* __restrict__ bucktot, int* __restrict__ buckbase)
{
    __shared__ int s[1024];
    int t = threadIdx.x;
    int v = (t < NBUCK) ? bucktot[t] : 0;
    s[t] = v;
    __syncthreads();
#pragma unroll
    for (int off = 1; off < 1024; off <<= 1) {
        int w = (t >= off) ? s[t - off] : 0;
        __syncthreads();
        s[t] += w;
        __syncthreads();
    }
    if (t < NBUCK) buckbase[t] = s[t] - v;
    if (t == 0) buckbase[NBUCK] = N_EDGES;
}

__global__ __launch_bounds__(256) void k_partition(
    const int* __restrict__ src, const int* __restrict__ dst,
    const float* __restrict__ u, const int* __restrict__ buckbase,
    const int* __restrict__ blk, int2* __restrict__ epb)
{
    __shared__ int rank[NBUCK];
    __shared__ int base_s[NBUCK];
    for (int i = threadIdx.x; i < NBUCK; i += 256) {
        rank[i] = 0;
        base_s[i] = buckbase[i] + blk[i * PB_NB + blockIdx.x];
    }
    __syncthreads();
    int ebase = blockIdx.x * PB_E;
#pragma unroll
    for (int k = 0; k < PB_E / 256; ++k) {
        int e = ebase + k * 256 + threadIdx.x;
        if (e < N_EDGES) {
            int d = dst[e];
            int b = d >> 6;
            int pos = base_s[b] + atomicAdd(&rank[b], 1);
            epb[pos] = make_int2((src[e] & 0xFFFF) | ((d & 63) << 16),
                                 __float_as_int(u[e]));
        }
    }
}

// ---------------------------------------------------------------------------
// Within-bucket counting sort (in LDS, in-place in global) -> full dst-CSR.
// One block per bucket: load <=BCAP edges to LDS, 64-bin hist, wave-scan,
// LDS scatter to second buffer, coalesced write-back, emit rowptr.
// ---------------------------------------------------------------------------
__global__ __launch_bounds__(256) void k_bsort(
    const int* __restrict__ buckbase, int2* __restrict__ epb,
    int* __restrict__ rowptr)
{
    __shared__ int2 buf[BCAP];
    __shared__ int2 sorted[BCAP];
    __shared__ int cnt[64], pre[64], cur[64];
    int b = blockIdx.x;
    int beg = buckbase[b], end = buckbase[b + 1];
    int m = min(end - beg, BCAP);

    if (threadIdx.x < 64) cnt[threadIdx.x] = 0;
    __syncthreads();
    for (int i = threadIdx.x; i < m; i += 256) {
        int2 p = epb[beg + i];
        buf[i] = p;
        atomicAdd(&cnt[(p.x >> 16) & 63], 1);
    }
    __syncthreads();
    if (threadIdx.x < 64) {
        int v = cnt[threadIdx.x];
        int s = v;
#pragma unroll
        for (int off = 1; off < 64; off <<= 1) {
            int w = __shfl_up(s, off);
            if (threadIdx.x >= off) s += w;
        }
        int ex = s - v;
        pre[threadIdx.x] = ex;
        cur[threadIdx.x] = ex;
        int n = (b << 6) + threadIdx.x;
        if (n <= N_NODES) rowptr[n] = beg + ex;   // covers rowptr[N_NODES]=N_EDGES
    }
    __syncthreads();
    for (int i = threadIdx.x; i < m; i += 256) {
        int2 p = buf[i];
        int pos = atomicAdd(&cur[(p.x >> 16) & 63], 1);
        sorted[pos] = p;
    }
    __syncthreads();
    for (int i = threadIdx.x; i < m; i += 256)
        epb[beg + i] = sorted[i];
}

// ---------------------------------------------------------------------------
// Gather-mean: wave per dst node, 8 edge slots x 8 lanes (2 features each,
// one float4 AB read per lane), 2x unrolled -> up to 16 loads in flight.
// ---------------------------------------------------------------------------
__global__ __launch_bounds__(256) void k_gather(
    const int* __restrict__ rowptr, const int2* __restrict__ ep,
    const float* __restrict__ AB, float* __restrict__ AGG)
{
    int n    = (blockIdx.x * 256 + threadIdx.x) >> 6;  // 12500 blocks -> 50000
    int lane = threadIdx.x & 63;
    int g = lane >> 3;   // edge slot 0..7
    int l = lane & 7;    // feature pair: feats 2l, 2l+1
    int beg = rowptr[n], end = rowptr[n + 1];
    float ax = 0.f, ay = 0.f;
    int e = beg + g;
    for (; e + 8 < end; e += 16) {
        int2 p0 = ep[e];
        int2 p1 = ep[e + 8];
        float u0 = __int_as_float(p0.y);
        float u1 = __int_as_float(p1.y);
        float4 h0 = *(const float4*)&AB[(size_t)(p0.x & 0xFFFF) * 32 + 4 * l];
        float4 h1 = *(const float4*)&AB[(size_t)(p1.x & 0xFFFF) * 32 + 4 * l];
        ax += (1.f - u0) * h0.x + u0 * h0.y;
        ay += (1.f - u0) * h0.z + u0 * h0.w;
        ax += (1.f - u1) * h1.x + u1 * h1.y;
        ay += (1.f - u1) * h1.z + u1 * h1.w;
    }
    if (e < end) {
        int2 p0 = ep[e];
        float u0 = __int_as_float(p0.y);
        float4 h0 = *(const float4*)&AB[(size_t)(p0.x & 0xFFFF) * 32 + 4 * l];
        ax += (1.f - u0) * h0.x + u0 * h0.y;
        ay += (1.f - u0) * h0.z + u0 * h0.w;
    }
#pragma unroll
    for (int s = 8; s < 64; s <<= 1) {
        ax += __shfl_xor(ax, s);
        ay += __shfl_xor(ay, s);
    }
    float dv = fmaxf((float)(end - beg), 1.f);
    if (lane < 8)
        *(float2*)&AGG[(size_t)n * 16 + 2 * lane] = make_float2(ax / dv, ay / dv);
}

// ---------------------------------------------------------------------------
// K3: finish layer 1 (agg already meaned) + ELU + layer-2 node transform.
// ---------------------------------------------------------------------------
__global__ __launch_bounds__(256) void k_node2(
    const float* __restrict__ agg, float* __restrict__ C,
    const float* __restrict__ w2, const float* __restrict__ root2,
    const float* __restrict__ b2, float* __restrict__ AB)
{
    __shared__ float W2[16 * 48];
    __shared__ float hl[16][17];
    for (int t = threadIdx.x; t < 16 * 48; t += 256) {
        int j = t / 48, o = t % 48;
        float v;
        if (o < 16)       v = w2[j * 16 + o];
        else if (o < 32)  v = w2[256 + j * 16 + (o - 16)];
        else              v = root2[j * 16 + (o - 32)];
        W2[t] = v;
    }
    int nl = threadIdx.x >> 4;
    int o  = threadIdx.x & 15;
    int n  = blockIdx.x * 16 + nl;

    float pre = agg[(size_t)n * 16 + o] + C[(size_t)n * 16 + o];
    float h   = pre > 0.f ? pre : expm1f(pre);
    __syncthreads();
    hl[nl][o] = h;
    __syncthreads();

    float a = 0.f, b = 0.f, p = 0.f;
#pragma unroll
    for (int j = 0; j < 16; ++j) {
        float hv = hl[nl][j];
        a += hv * W2[j * 48 + o];
        b += hv * W2[j * 48 + 16 + o];
        p += hv * W2[j * 48 + 32 + o];
    }
    *(float2*)&AB[(size_t)n * 32 + 2 * o] = make_float2(a, b);
    C[(size_t)n * 16 + o] = p + b2[o];
}

// ---------------------------------------------------------------------------
// K5: log_softmax over 16 classes.
// ---------------------------------------------------------------------------
__global__ __launch_bounds__(256) void k_final(
    const float* __restrict__ agg, const float* __restrict__ C,
    float* __restrict__ out)
{
    int t = blockIdx.x * 256 + threadIdx.x;
    int n = t >> 4;
    int o = t & 15;
    float v = agg[(size_t)n * 16 + o] + C[(size_t)n * 16 + o];
    float m = v;
#pragma unroll
    for (int s = 1; s < 16; s <<= 1) m = fmaxf(m, __shfl_xor(m, s, 16));
    float ex = __expf(v - m);
    float ssum = ex;
#pragma unroll
    for (int s = 1; s < 16; s <<= 1) ssum += __shfl_xor(ssum, s, 16);
    out[(size_t)n * 16 + o] = v - m - __logf(ssum);
}

extern "C" void kernel_launch(void* const* d_in, const int* in_sizes, int n_in,
                              void* d_out, int out_size, void* d_ws, size_t ws_size,
                              hipStream_t stream) {
    const float* x     = (const float*)d_in[0];
    const int*   ei    = (const int*)d_in[1];
    const float* ea    = (const float*)d_in[2];
    const float* w1    = (const float*)d_in[3];
    const float* root1 = (const float*)d_in[4];
    const float* b1    = (const float*)d_in[5];
    const float* w2    = (const float*)d_in[6];
    const float* root2 = (const float*)d_in[7];
    const float* b2    = (const float*)d_in[8];
    float* out = (float*)d_out;

    char* ws = (char*)d_ws;
    float* AB       = (float*)ws;                                   // N*32
    float* C        = AB + (size_t)N_NODES * 32;                    // N*16
    float* AGG      = C + (size_t)N_NODES * 16;                     // N*16
    int2*  EPB      = (int2*)(AGG + (size_t)N_NODES * 16);          // E int2
    int*   BLK      = (int*)(EPB + N_EDGES);                        // NBUCK*PB_NB
    int*   BUCKTOT  = BLK + NBUCK * PB_NB;                          // NBUCK
    int*   BUCKBASE = BUCKTOT + NBUCK;                              // NBUCK+1
    int*   ROWPTR   = BUCKBASE + (NBUCK + 1);                       // N+1

    const int* srcp = ei;
    const int* dstp = ei + N_EDGES;

    k_node1<<<782, 256, 0, stream>>>(x, w1, root1, b1, AB, C);
    k_histA<<<PB_NB, 256, 0, stream>>>(dstp, BLK);
    k_scanblk<<<NBUCK, 256, 0, stream>>>(BLK, BUCKTOT);
    k_scanbase<<<1, 1024, 0, stream>>>(BUCKTOT, BUCKBASE);
    k_partition<<<PB_NB, 256, 0, stream>>>(srcp, dstp, ea, BUCKBASE, BLK, EPB);
    k_bsort<<<NBUCK, 256, 0, stream>>>(BUCKBASE, EPB, ROWPTR);

    k_gather<<<N_NODES / 4, 256, 0, stream>>>(ROWPTR, EPB, AB, AGG);
    k_node2<<<N_NODES / 16, 256, 0, stream>>>(AGG, C, w2, root2, b2, AB);
    k_gather<<<N_NODES / 4, 256, 0, stream>>>(ROWPTR, EPB, AB, AGG);
    k_final<<<N_NODES / 16, 256, 0, stream>>>(AGG, C, out);
}

// Round 7
// 122.370 us; speedup vs baseline: 2.1098x; 1.0138x over previous
//
#include <hip/hip_runtime.h>
#include <hip/hip_bf16.h>
#include <math.h>

#define N_NODES 50000
#define N_EDGES 800000
#define N_FEAT 128
#define HIDDEN 16
#define N_CLASSES 16

#define NBUCK 782          // ceil(50000 / 64) buckets of 64 dst nodes
#define PB_NB 196          // partition blocks
#define PB_E  4096         // edges per partition block (196*4096 >= 800000)
#define BCAP  1600         // max edges per bucket (mean 1023, sd ~32 -> 18 sigma)

__device__ __forceinline__ float bf2f(unsigned int bits16) {
    return __uint_as_float(bits16 << 16);
}
__device__ __forceinline__ unsigned int f2bf_bits(float f) {
    __hip_bfloat16 h = __float2bfloat16(f);
    return (unsigned int)*reinterpret_cast<unsigned short*>(&h);
}

// ---------------------------------------------------------------------------
// K1: layer-1 node transform. h0 = x@w1[0], h1 = x@w1[1], p1 = x@root1 + b1.
// ABu[n][16] uints: uint o = (h1[o]<<16 | h0[o]) as bf16 -> 64B row; an
// 8-lane edge group reads uint2 per lane (feats 2l, 2l+1).
// ---------------------------------------------------------------------------
__global__ __launch_bounds__(256) void k_node1(
    const float* __restrict__ x, const float* __restrict__ w1,
    const float* __restrict__ root1, const float* __restrict__ b1,
    unsigned int* __restrict__ ABu, float* __restrict__ C)
{
    __shared__ float W[48 * 132];
    for (int t = threadIdx.x; t < 48 * 128; t += 256) {
        int o = t >> 7;
        int i = t & 127;
        float v;
        if (o < 16)       v = w1[i * 16 + o];
        else if (o < 32)  v = w1[2048 + i * 16 + (o - 16)];
        else              v = root1[i * 16 + (o - 32)];
        W[o * 132 + i] = v;
    }
    __syncthreads();

    int o = threadIdx.x & 15;
    int g = threadIdx.x >> 4;
    int nbase = blockIdx.x * 64 + g * 4;

    int n0 = min(nbase + 0, N_NODES - 1);
    int n1 = min(nbase + 1, N_NODES - 1);
    int n2 = min(nbase + 2, N_NODES - 1);
    int n3 = min(nbase + 3, N_NODES - 1);

    const float4* x0 = (const float4*)(x + (size_t)n0 * N_FEAT);
    const float4* x1 = (const float4*)(x + (size_t)n1 * N_FEAT);
    const float4* x2 = (const float4*)(x + (size_t)n2 * N_FEAT);
    const float4* x3 = (const float4*)(x + (size_t)n3 * N_FEAT);

    float acc[4][3];
#pragma unroll
    for (int j = 0; j < 4; ++j)
#pragma unroll
        for (int k = 0; k < 3; ++k) acc[j][k] = 0.f;

#pragma unroll 4
    for (int i4 = 0; i4 < 32; ++i4) {
        float4 wa = *(const float4*)&W[o * 132 + 4 * i4];
        float4 wb = *(const float4*)&W[(o + 16) * 132 + 4 * i4];
        float4 wr = *(const float4*)&W[(o + 32) * 132 + 4 * i4];
        float4 xv[4];
        xv[0] = x0[i4]; xv[1] = x1[i4]; xv[2] = x2[i4]; xv[3] = x3[i4];
#pragma unroll
        for (int j = 0; j < 4; ++j) {
            acc[j][0] += xv[j].x * wa.x + xv[j].y * wa.y + xv[j].z * wa.z + xv[j].w * wa.w;
            acc[j][1] += xv[j].x * wb.x + xv[j].y * wb.y + xv[j].z * wb.z + xv[j].w * wb.w;
            acc[j][2] += xv[j].x * wr.x + xv[j].y * wr.y + xv[j].z * wr.z + xv[j].w * wr.w;
        }
    }

    float bo = b1[o];
#pragma unroll
    for (int j = 0; j < 4; ++j) {
        int n = nbase + j;
        if (n < N_NODES) {
            ABu[(size_t)n * 16 + o] = (f2bf_bits(acc[j][1]) << 16) | f2bf_bits(acc[j][0]);
            C[(size_t)n * 16 + o] = acc[j][2] + bo;
        }
    }
}

// ---------------------------------------------------------------------------
// Bucket partition (64-node buckets): per-(bucket,block) hist in LDS, two
// small scans, then scatter with per-block-contiguous runs per bucket.
// Payload: {src | dst_local<<16, u}.
// ---------------------------------------------------------------------------
__global__ __launch_bounds__(256) void k_histA(
    const int* __restrict__ dst, int* __restrict__ blk)
{
    __shared__ int cnt[NBUCK];
    for (int i = threadIdx.x; i < NBUCK; i += 256) cnt[i] = 0;
    __syncthreads();
    int base = blockIdx.x * PB_E;
#pragma unroll
    for (int k = 0; k < PB_E / 256; ++k) {
        int e = base + k * 256 + threadIdx.x;
        if (e < N_EDGES) atomicAdd(&cnt[dst[e] >> 6], 1);
    }
    __syncthreads();
    for (int i = threadIdx.x; i < NBUCK; i += 256)
        blk[i * PB_NB + blockIdx.x] = cnt[i];
}

__global__ __launch_bounds__(256) void k_scanblk(
    int* __restrict__ blk, int* __restrict__ bucktot)
{
    __shared__ int s[256];
    int b = blockIdx.x, t = threadIdx.x;
    int v = (t < PB_NB) ? blk[b * PB_NB + t] : 0;
    s[t] = v;
    __syncthreads();
#pragma unroll
    for (int off = 1; off < 256; off <<= 1) {
        int w = (t >= off) ? s[t - off] : 0;
        __syncthreads();
        s[t] += w;
        __syncthreads();
    }
    if (t < PB_NB) blk[b * PB_NB + t] = s[t] - v;
    if (t == PB_NB - 1) bucktot[b] = s[t];
}

__global__ __launch_bounds__(1024) void k_scanbase(
    const int* __restrict__ bucktot, int* __restrict__ buckbase)
{
    __shared__ int s[1024];
    int t = threadIdx.x;
    int v = (t < NBUCK) ? bucktot[t] : 0;
    s[t] = v;
    __syncthreads();
#pragma unroll
    for (int off = 1; off < 1024; off <<= 1) {
        int w = (t >= off) ? s[t - off] : 0;
        __syncthreads();
        s[t] += w;
        __syncthreads();
    }
    if (t < NBUCK) buckbase[t] = s[t] - v;
    if (t == 0) buckbase[NBUCK] = N_EDGES;
}

__global__ __launch_bounds__(256) void k_partition(
    const int* __restrict__ src, const int* __restrict__ dst,
    const float* __restrict__ u, const int* __restrict__ buckbase,
    const int* __restrict__ blk, int2* __restrict__ epb)
{
    __shared__ int rank[NBUCK];
    __shared__ int base_s[NBUCK];
    for (int i = threadIdx.x; i < NBUCK; i += 256) {
        rank[i] = 0;
        base_s[i] = buckbase[i] + blk[i * PB_NB + blockIdx.x];
    }
    __syncthreads();
    int ebase = blockIdx.x * PB_E;
#pragma unroll
    for (int k = 0; k < PB_E / 256; ++k) {
        int e = ebase + k * 256 + threadIdx.x;
        if (e < N_EDGES) {
            int d = dst[e];
            int b = d >> 6;
            int pos = base_s[b] + atomicAdd(&rank[b], 1);
            epb[pos] = make_int2((src[e] & 0xFFFF) | ((d & 63) << 16),
                                 __float_as_int(u[e]));
        }
    }
}

// ---------------------------------------------------------------------------
// Within-bucket counting sort (in LDS, in-place in global) -> full dst-CSR.
// ---------------------------------------------------------------------------
__global__ __launch_bounds__(256) void k_bsort(
    const int* __restrict__ buckbase, int2* __restrict__ epb,
    int* __restrict__ rowptr)
{
    __shared__ int2 buf[BCAP];
    __shared__ int2 sorted[BCAP];
    __shared__ int cnt[64], cur[64];
    int b = blockIdx.x;
    int beg = buckbase[b], end = buckbase[b + 1];
    int m = min(end - beg, BCAP);

    if (threadIdx.x < 64) cnt[threadIdx.x] = 0;
    __syncthreads();
    for (int i = threadIdx.x; i < m; i += 256) {
        int2 p = epb[beg + i];
        buf[i] = p;
        atomicAdd(&cnt[(p.x >> 16) & 63], 1);
    }
    __syncthreads();
    if (threadIdx.x < 64) {
        int v = cnt[threadIdx.x];
        int s = v;
#pragma unroll
        for (int off = 1; off < 64; off <<= 1) {
            int w = __shfl_up(s, off);
            if (threadIdx.x >= off) s += w;
        }
        int ex = s - v;
        cur[threadIdx.x] = ex;
        int n = (b << 6) + threadIdx.x;
        if (n <= N_NODES) rowptr[n] = beg + ex;
    }
    __syncthreads();
    for (int i = threadIdx.x; i < m; i += 256) {
        int2 p = buf[i];
        int pos = atomicAdd(&cur[(p.x >> 16) & 63], 1);
        sorted[pos] = p;
    }
    __syncthreads();
    for (int i = threadIdx.x; i < m; i += 256)
        epb[beg + i] = sorted[i];
}

// ---------------------------------------------------------------------------
// Gather-mean (layer 1): wave per dst node, 8 edge slots x 8 lanes (feats
// 2l,2l+1 via one uint2 bf16 read), 2x unrolled. Writes meaned AGG (fp32).
// ---------------------------------------------------------------------------
__global__ __launch_bounds__(256) void k_gather1(
    const int* __restrict__ rowptr, const int2* __restrict__ ep,
    const unsigned int* __restrict__ ABu, float* __restrict__ AGG)
{
    int n    = (blockIdx.x * 256 + threadIdx.x) >> 6;
    int lane = threadIdx.x & 63;
    int g = lane >> 3;
    int l = lane & 7;
    int beg = rowptr[n], end = rowptr[n + 1];
    const uint2* AB2 = (const uint2*)ABu;
    float ax = 0.f, ay = 0.f;
    int e = beg + g;
    for (; e + 8 < end; e += 16) {
        int2 p0 = ep[e];
        int2 p1 = ep[e + 8];
        float u0 = __int_as_float(p0.y);
        float u1 = __int_as_float(p1.y);
        uint2 q0 = AB2[(size_t)(p0.x & 0xFFFF) * 8 + l];
        uint2 q1 = AB2[(size_t)(p1.x & 0xFFFF) * 8 + l];
        ax += (1.f - u0) * bf2f(q0.x & 0xFFFF) + u0 * bf2f(q0.x >> 16);
        ay += (1.f - u0) * bf2f(q0.y & 0xFFFF) + u0 * bf2f(q0.y >> 16);
        ax += (1.f - u1) * bf2f(q1.x & 0xFFFF) + u1 * bf2f(q1.x >> 16);
        ay += (1.f - u1) * bf2f(q1.y & 0xFFFF) + u1 * bf2f(q1.y >> 16);
    }
    if (e < end) {
        int2 p0 = ep[e];
        float u0 = __int_as_float(p0.y);
        uint2 q0 = AB2[(size_t)(p0.x & 0xFFFF) * 8 + l];
        ax += (1.f - u0) * bf2f(q0.x & 0xFFFF) + u0 * bf2f(q0.x >> 16);
        ay += (1.f - u0) * bf2f(q0.y & 0xFFFF) + u0 * bf2f(q0.y >> 16);
    }
#pragma unroll
    for (int s = 8; s < 64; s <<= 1) {
        ax += __shfl_xor(ax, s);
        ay += __shfl_xor(ay, s);
    }
    float dv = fmaxf((float)(end - beg), 1.f);
    if (lane < 8)
        *(float2*)&AGG[(size_t)n * 16 + 2 * lane] = make_float2(ax / dv, ay / dv);
}

// ---------------------------------------------------------------------------
// K3: finish layer 1 (agg already meaned) + ELU + layer-2 node transform.
// Writes packed bf16 ABu (layer-2 h0/h1) and C (p2, fp32).
// ---------------------------------------------------------------------------
__global__ __launch_bounds__(256) void k_node2(
    const float* __restrict__ agg, float* __restrict__ C,
    const float* __restrict__ w2, const float* __restrict__ root2,
    const float* __restrict__ b2, unsigned int* __restrict__ ABu)
{
    __shared__ float W2[16 * 48];
    __shared__ float hl[16][17];
    for (int t = threadIdx.x; t < 16 * 48; t += 256) {
        int j = t / 48, o = t % 48;
        float v;
        if (o < 16)       v = w2[j * 16 + o];
        else if (o < 32)  v = w2[256 + j * 16 + (o - 16)];
        else              v = root2[j * 16 + (o - 32)];
        W2[t] = v;
    }
    int nl = threadIdx.x >> 4;
    int o  = threadIdx.x & 15;
    int n  = blockIdx.x * 16 + nl;

    float pre = agg[(size_t)n * 16 + o] + C[(size_t)n * 16 + o];
    float h   = pre > 0.f ? pre : expm1f(pre);
    __syncthreads();
    hl[nl][o] = h;
    __syncthreads();

    float a = 0.f, b = 0.f, p = 0.f;
#pragma unroll
    for (int j = 0; j < 16; ++j) {
        float hv = hl[nl][j];
        a += hv * W2[j * 48 + o];
        b += hv * W2[j * 48 + 16 + o];
        p += hv * W2[j * 48 + 32 + o];
    }
    ABu[(size_t)n * 16 + o] = (f2bf_bits(b) << 16) | f2bf_bits(a);
    C[(size_t)n * 16 + o] = p + b2[o];
}

// ---------------------------------------------------------------------------
// Gather-mean (layer 2) + fused log_softmax: after the edge reduce, the
// 8-lane feature group holds the full 16-class row; 3 more shfl_xor levels
// give max and sum. Writes d_out directly.
// ---------------------------------------------------------------------------
__global__ __launch_bounds__(256) void k_gather2(
    const int* __restrict__ rowptr, const int2* __restrict__ ep,
    const unsigned int* __restrict__ ABu, const float* __restrict__ C,
    float* __restrict__ out)
{
    int n    = (blockIdx.x * 256 + threadIdx.x) >> 6;
    int lane = threadIdx.x & 63;
    int g = lane >> 3;
    int l = lane & 7;
    int beg = rowptr[n], end = rowptr[n + 1];
    const uint2* AB2 = (const uint2*)ABu;
    float ax = 0.f, ay = 0.f;
    int e = beg + g;
    for (; e + 8 < end; e += 16) {
        int2 p0 = ep[e];
        int2 p1 = ep[e + 8];
        float u0 = __int_as_float(p0.y);
        float u1 = __int_as_float(p1.y);
        uint2 q0 = AB2[(size_t)(p0.x & 0xFFFF) * 8 + l];
        uint2 q1 = AB2[(size_t)(p1.x & 0xFFFF) * 8 + l];
        ax += (1.f - u0) * bf2f(q0.x & 0xFFFF) + u0 * bf2f(q0.x >> 16);
        ay += (1.f - u0) * bf2f(q0.y & 0xFFFF) + u0 * bf2f(q0.y >> 16);
        ax += (1.f - u1) * bf2f(q1.x & 0xFFFF) + u1 * bf2f(q1.x >> 16);
        ay += (1.f - u1) * bf2f(q1.y & 0xFFFF) + u1 * bf2f(q1.y >> 16);
    }
    if (e < end) {
        int2 p0 = ep[e];
        float u0 = __int_as_float(p0.y);
        uint2 q0 = AB2[(size_t)(p0.x & 0xFFFF) * 8 + l];
        ax += (1.f - u0) * bf2f(q0.x & 0xFFFF) + u0 * bf2f(q0.x >> 16);
        ay += (1.f - u0) * bf2f(q0.y & 0xFFFF) + u0 * bf2f(q0.y >> 16);
    }
#pragma unroll
    for (int s = 8; s < 64; s <<= 1) {
        ax += __shfl_xor(ax, s);
        ay += __shfl_xor(ay, s);
    }
    float dv = fmaxf((float)(end - beg), 1.f);
    float2 cv = *(const float2*)&C[(size_t)n * 16 + 2 * l];
    float v0 = ax / dv + cv.x;
    float v1 = ay / dv + cv.y;

    float m = fmaxf(v0, v1);
#pragma unroll
    for (int s = 1; s < 8; s <<= 1) m = fmaxf(m, __shfl_xor(m, s));
    float ssum = __expf(v0 - m) + __expf(v1 - m);
#pragma unroll
    for (int s = 1; s < 8; s <<= 1) ssum += __shfl_xor(ssum, s);
    float lse = m + __logf(ssum);
    if (lane < 8)
        *(float2*)&out[(size_t)n * 16 + 2 * l] = make_float2(v0 - lse, v1 - lse);
}

extern "C" void kernel_launch(void* const* d_in, const int* in_sizes, int n_in,
                              void* d_out, int out_size, void* d_ws, size_t ws_size,
                              hipStream_t stream) {
    const float* x     = (const float*)d_in[0];
    const int*   ei    = (const int*)d_in[1];
    const float* ea    = (const float*)d_in[2];
    const float* w1    = (const float*)d_in[3];
    const float* root1 = (const float*)d_in[4];
    const float* b1    = (const float*)d_in[5];
    const float* w2    = (const float*)d_in[6];
    const float* root2 = (const float*)d_in[7];
    const float* b2    = (const float*)d_in[8];
    float* out = (float*)d_out;

    char* ws = (char*)d_ws;
    unsigned int* ABu = (unsigned int*)ws;                          // N*16 uint (bf16 pairs)
    float* C        = (float*)(ABu + (size_t)N_NODES * 16);         // N*16
    float* AGG      = C + (size_t)N_NODES * 16;                     // N*16
    int2*  EPB      = (int2*)(AGG + (size_t)N_NODES * 16);          // E int2
    int*   BLK      = (int*)(EPB + N_EDGES);                        // NBUCK*PB_NB
    int*   BUCKTOT  = BLK + NBUCK * PB_NB;                          // NBUCK
    int*   BUCKBASE = BUCKTOT + NBUCK;                              // NBUCK+1
    int*   ROWPTR   = BUCKBASE + (NBUCK + 1);                       // N+1

    const int* srcp = ei;
    const int* dstp = ei + N_EDGES;

    k_node1<<<782, 256, 0, stream>>>(x, w1, root1, b1, ABu, C);
    k_histA<<<PB_NB, 256, 0, stream>>>(dstp, BLK);
    k_scanblk<<<NBUCK, 256, 0, stream>>>(BLK, BUCKTOT);
    k_scanbase<<<1, 1024, 0, stream>>>(BUCKTOT, BUCKBASE);
    k_partition<<<PB_NB, 256, 0, stream>>>(srcp, dstp, ea, BUCKBASE, BLK, EPB);
    k_bsort<<<NBUCK, 256, 0, stream>>>(BUCKBASE, EPB, ROWPTR);

    k_gather1<<<N_NODES / 4, 256, 0, stream>>>(ROWPTR, EPB, ABu, AGG);
    k_node2<<<N_NODES / 16, 256, 0, stream>>>(AGG, C, w2, root2, b2, ABu);
    k_gather2<<<N_NODES / 4, 256, 0, stream>>>(ROWPTR, EPB, ABu, C, out);
}

// Round 8
// 96.932 us; speedup vs baseline: 2.6635x; 1.2624x over previous
//
#include <hip/hip_runtime.h>
#include <hip/hip_bf16.h>
#include <math.h>

#define N_NODES 50000
#define N_EDGES 800000
#define N_FEAT 128
#define HIDDEN 16
#define N_CLASSES 16

#define NBUCK 782          // ceil(50000 / 64) buckets of 64 dst nodes
#define PB_NB 196          // partition blocks
#define PB_E  4096         // edges per partition block (196*4096 >= 800000)
#define BCAP  1600         // max edges per bucket (mean 1023, sd ~32 -> 18 sigma)

typedef __attribute__((ext_vector_type(8))) short short8v;   // 8 bf16 (4 VGPR)
typedef __attribute__((ext_vector_type(4))) float floatx4;   // MFMA acc

__device__ __forceinline__ float bf2f(unsigned int bits16) {
    return __uint_as_float(bits16 << 16);
}
__device__ __forceinline__ unsigned int f2bf_bits(float f) {
    __hip_bfloat16 h = __float2bfloat16(f);
    return (unsigned int)*reinterpret_cast<unsigned short*>(&h);
}

// ---------------------------------------------------------------------------
// K1 (MFMA): layer-1 node transform as [N x 128] @ [128 x 48] bf16 GEMM.
// One wave per 16-node tile; 3 output tiles (h0, h1, root) x 4 K-chunks =
// 12 x mfma_f32_16x16x32_bf16, fp32 accumulate.
// Layouts (m89-verified family): A: row=lane&15, k=(lane>>4)*8+j;
// B: col=lane&15, k=(lane>>4)*8+j; C/D: col=lane&15, row=(lane>>4)*4+reg.
// Outputs: ABu[n][16] uint = (bf16(h1)<<16)|bf16(h0); C[n][16] = p1 fp32.
// ---------------------------------------------------------------------------
__global__ __launch_bounds__(256) void k_node1(
    const float* __restrict__ x, const float* __restrict__ w1,
    const float* __restrict__ root1, const float* __restrict__ b1,
    unsigned int* __restrict__ ABu, float* __restrict__ C)
{
    int lane = threadIdx.x & 63;
    int wid  = threadIdx.x >> 6;
    int m = lane & 15;          // A row / B col / D col
    int q = lane >> 4;          // k-group
    int nb = blockIdx.x * 64 + wid * 16;   // grid 782 -> covers 50048

    // --- B fragments: 3 operand matrices (w1[0], w1[1], root1), 4 k-chunks.
    // Wt[k][col]: w1 is [2][128][16], root1 [128][16]; col = m, k = c*32+q*8+j.
    short8v bf[3][4];
#pragma unroll
    for (int c = 0; c < 4; ++c) {
        int k0 = c * 32 + q * 8;
        const float* p0 = w1 + (size_t)k0 * 16 + m;
        const float* p1 = w1 + 2048 + (size_t)k0 * 16 + m;
        const float* p2 = root1 + (size_t)k0 * 16 + m;
#pragma unroll
        for (int j = 0; j < 8; ++j) {
            bf[0][c][j] = (short)f2bf_bits(p0[j * 16]);
            bf[1][c][j] = (short)f2bf_bits(p1[j * 16]);
            bf[2][c][j] = (short)f2bf_bits(p2[j * 16]);
        }
    }

    // --- A fragments: x rows (nodes), bf16-converted on the fly.
    int row = min(nb + m, N_NODES - 1);
    const float* xr = x + (size_t)row * N_FEAT;
    short8v af[4];
#pragma unroll
    for (int c = 0; c < 4; ++c) {
        int k0 = c * 32 + q * 8;
        float4 v0 = *(const float4*)(xr + k0);
        float4 v1 = *(const float4*)(xr + k0 + 4);
        af[c][0] = (short)f2bf_bits(v0.x); af[c][1] = (short)f2bf_bits(v0.y);
        af[c][2] = (short)f2bf_bits(v0.z); af[c][3] = (short)f2bf_bits(v0.w);
        af[c][4] = (short)f2bf_bits(v1.x); af[c][5] = (short)f2bf_bits(v1.y);
        af[c][6] = (short)f2bf_bits(v1.z); af[c][7] = (short)f2bf_bits(v1.w);
    }

    floatx4 acc0 = {0.f, 0.f, 0.f, 0.f};
    floatx4 acc1 = {0.f, 0.f, 0.f, 0.f};
    floatx4 acc2 = {0.f, 0.f, 0.f, 0.f};
#pragma unroll
    for (int c = 0; c < 4; ++c) {
        acc0 = __builtin_amdgcn_mfma_f32_16x16x32_bf16(af[c], bf[0][c], acc0, 0, 0, 0);
        acc1 = __builtin_amdgcn_mfma_f32_16x16x32_bf16(af[c], bf[1][c], acc1, 0, 0, 0);
        acc2 = __builtin_amdgcn_mfma_f32_16x16x32_bf16(af[c], bf[2][c], acc2, 0, 0, 0);
    }

    float bo = b1[m];
#pragma unroll
    for (int j = 0; j < 4; ++j) {
        int n = nb + q * 4 + j;
        if (n < N_NODES) {
            ABu[(size_t)n * 16 + m] = (f2bf_bits(acc1[j]) << 16) | f2bf_bits(acc0[j]);
            C[(size_t)n * 16 + m]   = acc2[j] + bo;
        }
    }
}

// ---------------------------------------------------------------------------
// Bucket partition (64-node buckets): per-(bucket,block) hist in LDS, two
// small scans, then scatter with per-block-contiguous runs per bucket.
// Payload: {src | dst_local<<16, u}.
// ---------------------------------------------------------------------------
__global__ __launch_bounds__(256) void k_histA(
    const int* __restrict__ dst, int* __restrict__ blk)
{
    __shared__ int cnt[NBUCK];
    for (int i = threadIdx.x; i < NBUCK; i += 256) cnt[i] = 0;
    __syncthreads();
    int base = blockIdx.x * PB_E;
#pragma unroll
    for (int k = 0; k < PB_E / 256; ++k) {
        int e = base + k * 256 + threadIdx.x;
        if (e < N_EDGES) atomicAdd(&cnt[dst[e] >> 6], 1);
    }
    __syncthreads();
    for (int i = threadIdx.x; i < NBUCK; i += 256)
        blk[i * PB_NB + blockIdx.x] = cnt[i];
}

__global__ __launch_bounds__(256) void k_scanblk(
    int* __restrict__ blk, int* __restrict__ bucktot)
{
    __shared__ int s[256];
    int b = blockIdx.x, t = threadIdx.x;
    int v = (t < PB_NB) ? blk[b * PB_NB + t] : 0;
    s[t] = v;
    __syncthreads();
#pragma unroll
    for (int off = 1; off < 256; off <<= 1) {
        int w = (t >= off) ? s[t - off] : 0;
        __syncthreads();
        s[t] += w;
        __syncthreads();
    }
    if (t < PB_NB) blk[b * PB_NB + t] = s[t] - v;
    if (t == PB_NB - 1) bucktot[b] = s[t];
}

__global__ __launch_bounds__(1024) void k_scanbase(
    const int* __restrict__ bucktot, int* __restrict__ buckbase)
{
    __shared__ int s[1024];
    int t = threadIdx.x;
    int v = (t < NBUCK) ? bucktot[t] : 0;
    s[t] = v;
    __syncthreads();
#pragma unroll
    for (int off = 1; off < 1024; off <<= 1) {
        int w = (t >= off) ? s[t - off] : 0;
        __syncthreads();
        s[t] += w;
        __syncthreads();
    }
    if (t < NBUCK) buckbase[t] = s[t] - v;
    if (t == 0) buckbase[NBUCK] = N_EDGES;
}

__global__ __launch_bounds__(256) void k_partition(
    const int* __restrict__ src, const int* __restrict__ dst,
    const float* __restrict__ u, const int* __restrict__ buckbase,
    const int* __restrict__ blk, int2* __restrict__ epb)
{
    __shared__ int rank[NBUCK];
    __shared__ int base_s[NBUCK];
    for (int i = threadIdx.x; i < NBUCK; i += 256) {
        rank[i] = 0;
        base_s[i] = buckbase[i] + blk[i * PB_NB + blockIdx.x];
    }
    __syncthreads();
    int ebase = blockIdx.x * PB_E;
#pragma unroll
    for (int k = 0; k < PB_E / 256; ++k) {
        int e = ebase + k * 256 + threadIdx.x;
        if (e < N_EDGES) {
            int d = dst[e];
            int b = d >> 6;
            int pos = base_s[b] + atomicAdd(&rank[b], 1);
            epb[pos] = make_int2((src[e] & 0xFFFF) | ((d & 63) << 16),
                                 __float_as_int(u[e]));
        }
    }
}

// ---------------------------------------------------------------------------
// Within-bucket counting sort (in LDS, in-place in global) -> full dst-CSR.
// ---------------------------------------------------------------------------
__global__ __launch_bounds__(256) void k_bsort(
    const int* __restrict__ buckbase, int2* __restrict__ epb,
    int* __restrict__ rowptr)
{
    __shared__ int2 buf[BCAP];
    __shared__ int2 sorted[BCAP];
    __shared__ int cnt[64], cur[64];
    int b = blockIdx.x;
    int beg = buckbase[b], end = buckbase[b + 1];
    int m = min(end - beg, BCAP);

    if (threadIdx.x < 64) cnt[threadIdx.x] = 0;
    __syncthreads();
    for (int i = threadIdx.x; i < m; i += 256) {
        int2 p = epb[beg + i];
        buf[i] = p;
        atomicAdd(&cnt[(p.x >> 16) & 63], 1);
    }
    __syncthreads();
    if (threadIdx.x < 64) {
        int v = cnt[threadIdx.x];
        int s = v;
#pragma unroll
        for (int off = 1; off < 64; off <<= 1) {
            int w = __shfl_up(s, off);
            if (threadIdx.x >= off) s += w;
        }
        int ex = s - v;
        cur[threadIdx.x] = ex;
        int n = (b << 6) + threadIdx.x;
        if (n <= N_NODES) rowptr[n] = beg + ex;
    }
    __syncthreads();
    for (int i = threadIdx.x; i < m; i += 256) {
        int2 p = buf[i];
        int pos = atomicAdd(&cur[(p.x >> 16) & 63], 1);
        sorted[pos] = p;
    }
    __syncthreads();
    for (int i = threadIdx.x; i < m; i += 256)
        epb[beg + i] = sorted[i];
}

// ---------------------------------------------------------------------------
// Gather-mean (layer 1): wave per dst node, 8 edge slots x 8 lanes (feats
// 2l,2l+1 via one uint2 bf16 read), 2x unrolled. Writes meaned AGG (fp32).
// ---------------------------------------------------------------------------
__global__ __launch_bounds__(256) void k_gather1(
    const int* __restrict__ rowptr, const int2* __restrict__ ep,
    const unsigned int* __restrict__ ABu, float* __restrict__ AGG)
{
    int n    = (blockIdx.x * 256 + threadIdx.x) >> 6;
    int lane = threadIdx.x & 63;
    int g = lane >> 3;
    int l = lane & 7;
    int beg = rowptr[n], end = rowptr[n + 1];
    const uint2* AB2 = (const uint2*)ABu;
    float ax = 0.f, ay = 0.f;
    int e = beg + g;
    for (; e + 8 < end; e += 16) {
        int2 p0 = ep[e];
        int2 p1 = ep[e + 8];
        float u0 = __int_as_float(p0.y);
        float u1 = __int_as_float(p1.y);
        uint2 q0 = AB2[(size_t)(p0.x & 0xFFFF) * 8 + l];
        uint2 q1 = AB2[(size_t)(p1.x & 0xFFFF) * 8 + l];
        ax += (1.f - u0) * bf2f(q0.x & 0xFFFF) + u0 * bf2f(q0.x >> 16);
        ay += (1.f - u0) * bf2f(q0.y & 0xFFFF) + u0 * bf2f(q0.y >> 16);
        ax += (1.f - u1) * bf2f(q1.x & 0xFFFF) + u1 * bf2f(q1.x >> 16);
        ay += (1.f - u1) * bf2f(q1.y & 0xFFFF) + u1 * bf2f(q1.y >> 16);
    }
    if (e < end) {
        int2 p0 = ep[e];
        float u0 = __int_as_float(p0.y);
        uint2 q0 = AB2[(size_t)(p0.x & 0xFFFF) * 8 + l];
        ax += (1.f - u0) * bf2f(q0.x & 0xFFFF) + u0 * bf2f(q0.x >> 16);
        ay += (1.f - u0) * bf2f(q0.y & 0xFFFF) + u0 * bf2f(q0.y >> 16);
    }
#pragma unroll
    for (int s = 8; s < 64; s <<= 1) {
        ax += __shfl_xor(ax, s);
        ay += __shfl_xor(ay, s);
    }
    float dv = fmaxf((float)(end - beg), 1.f);
    if (lane < 8)
        *(float2*)&AGG[(size_t)n * 16 + 2 * lane] = make_float2(ax / dv, ay / dv);
}

// ---------------------------------------------------------------------------
// K3: finish layer 1 (agg already meaned) + ELU + layer-2 node transform.
// Writes packed bf16 ABu (layer-2 h0/h1) and C (p2, fp32).
// ---------------------------------------------------------------------------
__global__ __launch_bounds__(256) void k_node2(
    const float* __restrict__ agg, float* __restrict__ C,
    const float* __restrict__ w2, const float* __restrict__ root2,
    const float* __restrict__ b2, unsigned int* __restrict__ ABu)
{
    __shared__ float W2[16 * 48];
    __shared__ float hl[16][17];
    for (int t = threadIdx.x; t < 16 * 48; t += 256) {
        int j = t / 48, o = t % 48;
        float v;
        if (o < 16)       v = w2[j * 16 + o];
        else if (o < 32)  v = w2[256 + j * 16 + (o - 16)];
        else              v = root2[j * 16 + (o - 32)];
        W2[t] = v;
    }
    int nl = threadIdx.x >> 4;
    int o  = threadIdx.x & 15;
    int n  = blockIdx.x * 16 + nl;

    float pre = agg[(size_t)n * 16 + o] + C[(size_t)n * 16 + o];
    float h   = pre > 0.f ? pre : expm1f(pre);
    __syncthreads();
    hl[nl][o] = h;
    __syncthreads();

    float a = 0.f, b = 0.f, p = 0.f;
#pragma unroll
    for (int j = 0; j < 16; ++j) {
        float hv = hl[nl][j];
        a += hv * W2[j * 48 + o];
        b += hv * W2[j * 48 + 16 + o];
        p += hv * W2[j * 48 + 32 + o];
    }
    ABu[(size_t)n * 16 + o] = (f2bf_bits(b) << 16) | f2bf_bits(a);
    C[(size_t)n * 16 + o] = p + b2[o];
}

// ---------------------------------------------------------------------------
// Gather-mean (layer 2) + fused log_softmax -> d_out.
// ---------------------------------------------------------------------------
__global__ __launch_bounds__(256) void k_gather2(
    const int* __restrict__ rowptr, const int2* __restrict__ ep,
    const unsigned int* __restrict__ ABu, const float* __restrict__ C,
    float* __restrict__ out)
{
    int n    = (blockIdx.x * 256 + threadIdx.x) >> 6;
    int lane = threadIdx.x & 63;
    int g = lane >> 3;
    int l = lane & 7;
    int beg = rowptr[n], end = rowptr[n + 1];
    const uint2* AB2 = (const uint2*)ABu;
    float ax = 0.f, ay = 0.f;
    int e = beg + g;
    for (; e + 8 < end; e += 16) {
        int2 p0 = ep[e];
        int2 p1 = ep[e + 8];
        float u0 = __int_as_float(p0.y);
        float u1 = __int_as_float(p1.y);
        uint2 q0 = AB2[(size_t)(p0.x & 0xFFFF) * 8 + l];
        uint2 q1 = AB2[(size_t)(p1.x & 0xFFFF) * 8 + l];
        ax += (1.f - u0) * bf2f(q0.x & 0xFFFF) + u0 * bf2f(q0.x >> 16);
        ay += (1.f - u0) * bf2f(q0.y & 0xFFFF) + u0 * bf2f(q0.y >> 16);
        ax += (1.f - u1) * bf2f(q1.x & 0xFFFF) + u1 * bf2f(q1.x >> 16);
        ay += (1.f - u1) * bf2f(q1.y & 0xFFFF) + u1 * bf2f(q1.y >> 16);
    }
    if (e < end) {
        int2 p0 = ep[e];
        float u0 = __int_as_float(p0.y);
        uint2 q0 = AB2[(size_t)(p0.x & 0xFFFF) * 8 + l];
        ax += (1.f - u0) * bf2f(q0.x & 0xFFFF) + u0 * bf2f(q0.x >> 16);
        ay += (1.f - u0) * bf2f(q0.y & 0xFFFF) + u0 * bf2f(q0.y >> 16);
    }
#pragma unroll
    for (int s = 8; s < 64; s <<= 1) {
        ax += __shfl_xor(ax, s);
        ay += __shfl_xor(ay, s);
    }
    float dv = fmaxf((float)(end - beg), 1.f);
    float2 cv = *(const float2*)&C[(size_t)n * 16 + 2 * l];
    float v0 = ax / dv + cv.x;
    float v1 = ay / dv + cv.y;

    float m = fmaxf(v0, v1);
#pragma unroll
    for (int s = 1; s < 8; s <<= 1) m = fmaxf(m, __shfl_xor(m, s));
    float ssum = __expf(v0 - m) + __expf(v1 - m);
#pragma unroll
    for (int s = 1; s < 8; s <<= 1) ssum += __shfl_xor(ssum, s);
    float lse = m + __logf(ssum);
    if (lane < 8)
        *(float2*)&out[(size_t)n * 16 + 2 * l] = make_float2(v0 - lse, v1 - lse);
}

extern "C" void kernel_launch(void* const* d_in, const int* in_sizes, int n_in,
                              void* d_out, int out_size, void* d_ws, size_t ws_size,
                              hipStream_t stream) {
    const float* x     = (const float*)d_in[0];
    const int*   ei    = (const int*)d_in[1];
    const float* ea    = (const float*)d_in[2];
    const float* w1    = (const float*)d_in[3];
    const float* root1 = (const float*)d_in[4];
    const float* b1    = (const float*)d_in[5];
    const float* w2    = (const float*)d_in[6];
    const float* root2 = (const float*)d_in[7];
    const float* b2    = (const float*)d_in[8];
    float* out = (float*)d_out;

    char* ws = (char*)d_ws;
    unsigned int* ABu = (unsigned int*)ws;                          // N*16 uint (bf16 pairs)
    float* C        = (float*)(ABu + (size_t)N_NODES * 16);         // N*16
    float* AGG      = C + (size_t)N_NODES * 16;                     // N*16
    int2*  EPB      = (int2*)(AGG + (size_t)N_NODES * 16);          // E int2
    int*   BLK      = (int*)(EPB + N_EDGES);                        // NBUCK*PB_NB
    int*   BUCKTOT  = BLK + NBUCK * PB_NB;                          // NBUCK
    int*   BUCKBASE = BUCKTOT + NBUCK;                              // NBUCK+1
    int*   ROWPTR   = BUCKBASE + (NBUCK + 1);                       // N+1

    const int* srcp = ei;
    const int* dstp = ei + N_EDGES;

    k_node1<<<782, 256, 0, stream>>>(x, w1, root1, b1, ABu, C);
    k_histA<<<PB_NB, 256, 0, stream>>>(dstp, BLK);
    k_scanblk<<<NBUCK, 256, 0, stream>>>(BLK, BUCKTOT);
    k_scanbase<<<1, 1024, 0, stream>>>(BUCKTOT, BUCKBASE);
    k_partition<<<PB_NB, 256, 0, stream>>>(srcp, dstp, ea, BUCKBASE, BLK, EPB);
    k_bsort<<<NBUCK, 256, 0, stream>>>(BUCKBASE, EPB, ROWPTR);

    k_gather1<<<N_NODES / 4, 256, 0, stream>>>(ROWPTR, EPB, ABu, AGG);
    k_node2<<<N_NODES / 16, 256, 0, stream>>>(AGG, C, w2, root2, b2, ABu);
    k_gather2<<<N_NODES / 4, 256, 0, stream>>>(ROWPTR, EPB, ABu, C, out);
}

// Round 9
// 96.460 us; speedup vs baseline: 2.6765x; 1.0049x over previous
//
#include <hip/hip_runtime.h>
#include <hip/hip_bf16.h>
#include <math.h>

#define N_NODES 50000
#define N_EDGES 800000
#define N_FEAT 128
#define HIDDEN 16
#define N_CLASSES 16

#define NBUCK 782          // ceil(50000 / 64) buckets of 64 dst nodes
#define PB_NB 196          // partition blocks
#define PB_E  4096         // edges per partition block (196*4096 >= 800000)
#define BCAP  1600         // padded slots per bucket (mean 1023, sd ~32)

typedef __attribute__((ext_vector_type(8))) short short8v;   // 8 bf16 (4 VGPR)
typedef __attribute__((ext_vector_type(4))) float floatx4;   // MFMA acc

__device__ __forceinline__ float bf2f(unsigned int bits16) {
    return __uint_as_float(bits16 << 16);
}
__device__ __forceinline__ unsigned int f2bf_bits(float f) {
    __hip_bfloat16 h = __float2bfloat16(f);
    return (unsigned int)*reinterpret_cast<unsigned short*>(&h);
}

// ---------------------------------------------------------------------------
// K1 (MFMA): layer-1 node transform as [N x 128] @ [128 x 48] bf16 GEMM.
// One wave per 16-node tile; 3 output tiles (h0, h1, root) x 4 K-chunks =
// 12 x mfma_f32_16x16x32_bf16, fp32 accumulate.
// A: row=lane&15, k=(lane>>4)*8+j; B: col=lane&15, same k;
// C/D: col=lane&15, row=(lane>>4)*4+reg.
// ---------------------------------------------------------------------------
__global__ __launch_bounds__(256) void k_node1(
    const float* __restrict__ x, const float* __restrict__ w1,
    const float* __restrict__ root1, const float* __restrict__ b1,
    unsigned int* __restrict__ ABu, float* __restrict__ C)
{
    int lane = threadIdx.x & 63;
    int wid  = threadIdx.x >> 6;
    int m = lane & 15;
    int q = lane >> 4;
    int nb = blockIdx.x * 64 + wid * 16;   // grid 782 -> covers 50048

    short8v bf[3][4];
#pragma unroll
    for (int c = 0; c < 4; ++c) {
        int k0 = c * 32 + q * 8;
        const float* p0 = w1 + (size_t)k0 * 16 + m;
        const float* p1 = w1 + 2048 + (size_t)k0 * 16 + m;
        const float* p2 = root1 + (size_t)k0 * 16 + m;
#pragma unroll
        for (int j = 0; j < 8; ++j) {
            bf[0][c][j] = (short)f2bf_bits(p0[j * 16]);
            bf[1][c][j] = (short)f2bf_bits(p1[j * 16]);
            bf[2][c][j] = (short)f2bf_bits(p2[j * 16]);
        }
    }

    int row = min(nb + m, N_NODES - 1);
    const float* xr = x + (size_t)row * N_FEAT;
    short8v af[4];
#pragma unroll
    for (int c = 0; c < 4; ++c) {
        int k0 = c * 32 + q * 8;
        float4 v0 = *(const float4*)(xr + k0);
        float4 v1 = *(const float4*)(xr + k0 + 4);
        af[c][0] = (short)f2bf_bits(v0.x); af[c][1] = (short)f2bf_bits(v0.y);
        af[c][2] = (short)f2bf_bits(v0.z); af[c][3] = (short)f2bf_bits(v0.w);
        af[c][4] = (short)f2bf_bits(v1.x); af[c][5] = (short)f2bf_bits(v1.y);
        af[c][6] = (short)f2bf_bits(v1.z); af[c][7] = (short)f2bf_bits(v1.w);
    }

    floatx4 acc0 = {0.f, 0.f, 0.f, 0.f};
    floatx4 acc1 = {0.f, 0.f, 0.f, 0.f};
    floatx4 acc2 = {0.f, 0.f, 0.f, 0.f};
#pragma unroll
    for (int c = 0; c < 4; ++c) {
        acc0 = __builtin_amdgcn_mfma_f32_16x16x32_bf16(af[c], bf[0][c], acc0, 0, 0, 0);
        acc1 = __builtin_amdgcn_mfma_f32_16x16x32_bf16(af[c], bf[1][c], acc1, 0, 0, 0);
        acc2 = __builtin_amdgcn_mfma_f32_16x16x32_bf16(af[c], bf[2][c], acc2, 0, 0, 0);
    }

    float bo = b1[m];
#pragma unroll
    for (int j = 0; j < 4; ++j) {
        int n = nb + q * 4 + j;
        if (n < N_NODES) {
            ABu[(size_t)n * 16 + m] = (f2bf_bits(acc1[j]) << 16) | f2bf_bits(acc0[j]);
            C[(size_t)n * 16 + m]   = acc2[j] + bo;
        }
    }
}

// ---------------------------------------------------------------------------
// Fused bucket partition (replaces hist + 2 scans + partition):
// per-block LDS hist -> one global atomicAdd per (bucket,block) reserves a
// run inside the bucket's FIXED padded region [b*BCAP, (b+1)*BCAP) -> scatter.
// Payload: {src | dst_local<<16, u}. rank[b] ends as the bucket's edge count.
// ---------------------------------------------------------------------------
__global__ __launch_bounds__(256) void k_part(
    const int* __restrict__ src, const int* __restrict__ dst,
    const float* __restrict__ u, int* __restrict__ rank,
    int2* __restrict__ epb)
{
    __shared__ int cnt[NBUCK];   // pass 1: counts; pass 2: global cursors
    for (int i = threadIdx.x; i < NBUCK; i += 256) cnt[i] = 0;
    __syncthreads();
    int ebase = blockIdx.x * PB_E;
    int myd[PB_E / 256];
#pragma unroll
    for (int k = 0; k < PB_E / 256; ++k) {
        int e = ebase + k * 256 + threadIdx.x;
        myd[k] = (e < N_EDGES) ? dst[e] : -1;
        if (myd[k] >= 0) atomicAdd(&cnt[myd[k] >> 6], 1);
    }
    __syncthreads();
    for (int i = threadIdx.x; i < NBUCK; i += 256) {
        int c = cnt[i];
        int base = (c > 0) ? atomicAdd(&rank[i], c) : 0;
        cnt[i] = i * BCAP + base;
    }
    __syncthreads();
#pragma unroll
    for (int k = 0; k < PB_E / 256; ++k) {
        if (myd[k] >= 0) {
            int e = ebase + k * 256 + threadIdx.x;
            int b = myd[k] >> 6;
            int pos = atomicAdd(&cnt[b], 1);
            if (pos < (b + 1) * BCAP)   // overflow insurance (18-sigma)
                epb[pos] = make_int2((src[e] & 0xFFFF) | ((myd[k] & 63) << 16),
                                     __float_as_int(u[e]));
        }
    }
}

// ---------------------------------------------------------------------------
// Within-bucket counting sort (LDS, in-place in the padded region) ->
// per-node rowbeg/rowend (padded layout breaks rowptr adjacency).
// ---------------------------------------------------------------------------
__global__ __launch_bounds__(256) void k_bsort(
    const int* __restrict__ rank, int2* __restrict__ epb,
    int* __restrict__ rowbeg, int* __restrict__ rowend)
{
    __shared__ int2 buf[BCAP];
    __shared__ int2 sorted[BCAP];
    __shared__ int cnt[64], cur[64];
    int b = blockIdx.x;
    int beg = b * BCAP;
    int m = min(rank[b], BCAP);

    if (threadIdx.x < 64) cnt[threadIdx.x] = 0;
    __syncthreads();
    for (int i = threadIdx.x; i < m; i += 256) {
        int2 p = epb[beg + i];
        buf[i] = p;
        atomicAdd(&cnt[(p.x >> 16) & 63], 1);
    }
    __syncthreads();
    if (threadIdx.x < 64) {
        int v = cnt[threadIdx.x];
        int s = v;
#pragma unroll
        for (int off = 1; off < 64; off <<= 1) {
            int w = __shfl_up(s, off);
            if (threadIdx.x >= off) s += w;
        }
        int ex = s - v;
        cur[threadIdx.x] = ex;
        int n = (b << 6) + threadIdx.x;
        if (n < N_NODES) {
            rowbeg[n] = beg + ex;
            rowend[n] = beg + ex + v;
        }
    }
    __syncthreads();
    for (int i = threadIdx.x; i < m; i += 256) {
        int2 p = buf[i];
        int pos = atomicAdd(&cur[(p.x >> 16) & 63], 1);
        sorted[pos] = p;
    }
    __syncthreads();
    for (int i = threadIdx.x; i < m; i += 256)
        epb[beg + i] = sorted[i];
}

// ---------------------------------------------------------------------------
// Fused gather1 + node2: wave per dst node. Gather-mean (8 edge slots x
// 8 lanes, uint2 bf16 reads), then in-wave: ELU, h broadcast via shfl,
// 48-output layer-2 transform against LDS W2. Writes layer-2 ABu2 (bf16
// packed) and C2 (p2, fp32) -- separate buffers, ABu/C still being read.
// ---------------------------------------------------------------------------
__global__ __launch_bounds__(256) void k_gfused1(
    const int* __restrict__ rowbeg, const int* __restrict__ rowend,
    const int2* __restrict__ ep, const unsigned int* __restrict__ ABu,
    const float* __restrict__ C, const float* __restrict__ w2,
    const float* __restrict__ root2, const float* __restrict__ b2,
    unsigned int* __restrict__ ABu2, float* __restrict__ C2)
{
    __shared__ float W2s[16 * 48];  // cols 0..15 w2[0], 16..31 w2[1], 32..47 root2
    for (int t = threadIdx.x; t < 16 * 48; t += 256) {
        int j = t / 48, o = t % 48;
        float v;
        if (o < 16)       v = w2[j * 16 + o];
        else if (o < 32)  v = w2[256 + j * 16 + (o - 16)];
        else              v = root2[j * 16 + (o - 32)];
        W2s[t] = v;
    }
    __syncthreads();

    int n    = (blockIdx.x * 256 + threadIdx.x) >> 6;  // 12500 blocks -> 50000
    int lane = threadIdx.x & 63;
    int g = lane >> 3;
    int l = lane & 7;
    int beg = rowbeg[n], end = rowend[n];
    const uint2* AB2 = (const uint2*)ABu;
    float ax = 0.f, ay = 0.f;
    int e = beg + g;
    for (; e + 8 < end; e += 16) {
        int2 p0 = ep[e];
        int2 p1 = ep[e + 8];
        float u0 = __int_as_float(p0.y);
        float u1 = __int_as_float(p1.y);
        uint2 q0 = AB2[(size_t)(p0.x & 0xFFFF) * 8 + l];
        uint2 q1 = AB2[(size_t)(p1.x & 0xFFFF) * 8 + l];
        ax += (1.f - u0) * bf2f(q0.x & 0xFFFF) + u0 * bf2f(q0.x >> 16);
        ay += (1.f - u0) * bf2f(q0.y & 0xFFFF) + u0 * bf2f(q0.y >> 16);
        ax += (1.f - u1) * bf2f(q1.x & 0xFFFF) + u1 * bf2f(q1.x >> 16);
        ay += (1.f - u1) * bf2f(q1.y & 0xFFFF) + u1 * bf2f(q1.y >> 16);
    }
    if (e < end) {
        int2 p0 = ep[e];
        float u0 = __int_as_float(p0.y);
        uint2 q0 = AB2[(size_t)(p0.x & 0xFFFF) * 8 + l];
        ax += (1.f - u0) * bf2f(q0.x & 0xFFFF) + u0 * bf2f(q0.x >> 16);
        ay += (1.f - u0) * bf2f(q0.y & 0xFFFF) + u0 * bf2f(q0.y >> 16);
    }
#pragma unroll
    for (int s = 8; s < 64; s <<= 1) {
        ax += __shfl_xor(ax, s);
        ay += __shfl_xor(ay, s);
    }
    // lanes with the same l now all hold the meaned sums for feats 2l, 2l+1
    float dv = fmaxf((float)(end - beg), 1.f);
    float2 cv = *(const float2*)&C[(size_t)n * 16 + 2 * l];
    float pre0 = ax / dv + cv.x;
    float pre1 = ay / dv + cv.y;
    float h0 = pre0 > 0.f ? pre0 : expm1f(pre0);
    float h1 = pre1 > 0.f ? pre1 : expm1f(pre1);

    // layer-2: lane o (0..47) computes output column o of [h @ (w2|w2|root2)]
    int oc = (lane < 48) ? lane : 0;
    float val = 0.f;
#pragma unroll
    for (int j2 = 0; j2 < 8; ++j2) {
        float hh0 = __shfl(h0, j2);   // h[2*j2]
        float hh1 = __shfl(h1, j2);   // h[2*j2+1]
        val += hh0 * W2s[(2 * j2) * 48 + oc] + hh1 * W2s[(2 * j2 + 1) * 48 + oc];
    }
    float bval = __shfl(val, (lane + 16) & 63);   // lanes 0..15: b from 16..31
    if (lane < 16)
        ABu2[(size_t)n * 16 + lane] = (f2bf_bits(bval) << 16) | f2bf_bits(val);
    else if (lane >= 32 && lane < 48)
        C2[(size_t)n * 16 + (lane - 32)] = val + b2[lane - 32];
}

// ---------------------------------------------------------------------------
// Gather-mean (layer 2) + fused log_softmax -> d_out.
// ---------------------------------------------------------------------------
__global__ __launch_bounds__(256) void k_gather2(
    const int* __restrict__ rowbeg, const int* __restrict__ rowend,
    const int2* __restrict__ ep, const unsigned int* __restrict__ ABu,
    const float* __restrict__ C, float* __restrict__ out)
{
    int n    = (blockIdx.x * 256 + threadIdx.x) >> 6;
    int lane = threadIdx.x & 63;
    int g = lane >> 3;
    int l = lane & 7;
    int beg = rowbeg[n], end = rowend[n];
    const uint2* AB2 = (const uint2*)ABu;
    float ax = 0.f, ay = 0.f;
    int e = beg + g;
    for (; e + 8 < end; e += 16) {
        int2 p0 = ep[e];
        int2 p1 = ep[e + 8];
        float u0 = __int_as_float(p0.y);
        float u1 = __int_as_float(p1.y);
        uint2 q0 = AB2[(size_t)(p0.x & 0xFFFF) * 8 + l];
        uint2 q1 = AB2[(size_t)(p1.x & 0xFFFF) * 8 + l];
        ax += (1.f - u0) * bf2f(q0.x & 0xFFFF) + u0 * bf2f(q0.x >> 16);
        ay += (1.f - u0) * bf2f(q0.y & 0xFFFF) + u0 * bf2f(q0.y >> 16);
        ax += (1.f - u1) * bf2f(q1.x & 0xFFFF) + u1 * bf2f(q1.x >> 16);
        ay += (1.f - u1) * bf2f(q1.y & 0xFFFF) + u1 * bf2f(q1.y >> 16);
    }
    if (e < end) {
        int2 p0 = ep[e];
        float u0 = __int_as_float(p0.y);
        uint2 q0 = AB2[(size_t)(p0.x & 0xFFFF) * 8 + l];
        ax += (1.f - u0) * bf2f(q0.x & 0xFFFF) + u0 * bf2f(q0.x >> 16);
        ay += (1.f - u0) * bf2f(q0.y & 0xFFFF) + u0 * bf2f(q0.y >> 16);
    }
#pragma unroll
    for (int s = 8; s < 64; s <<= 1) {
        ax += __shfl_xor(ax, s);
        ay += __shfl_xor(ay, s);
    }
    float dv = fmaxf((float)(end - beg), 1.f);
    float2 cv = *(const float2*)&C[(size_t)n * 16 + 2 * l];
    float v0 = ax / dv + cv.x;
    float v1 = ay / dv + cv.y;

    float m = fmaxf(v0, v1);
#pragma unroll
    for (int s = 1; s < 8; s <<= 1) m = fmaxf(m, __shfl_xor(m, s));
    float ssum = __expf(v0 - m) + __expf(v1 - m);
#pragma unroll
    for (int s = 1; s < 8; s <<= 1) ssum += __shfl_xor(ssum, s);
    float lse = m + __logf(ssum);
    if (lane < 8)
        *(float2*)&out[(size_t)n * 16 + 2 * l] = make_float2(v0 - lse, v1 - lse);
}

extern "C" void kernel_launch(void* const* d_in, const int* in_sizes, int n_in,
                              void* d_out, int out_size, void* d_ws, size_t ws_size,
                              hipStream_t stream) {
    const float* x     = (const float*)d_in[0];
    const int*   ei    = (const int*)d_in[1];
    const float* ea    = (const float*)d_in[2];
    const float* w1    = (const float*)d_in[3];
    const float* root1 = (const float*)d_in[4];
    const float* b1    = (const float*)d_in[5];
    const float* w2    = (const float*)d_in[6];
    const float* root2 = (const float*)d_in[7];
    const float* b2    = (const float*)d_in[8];
    float* out = (float*)d_out;

    char* ws = (char*)d_ws;
    unsigned int* ABu  = (unsigned int*)ws;                         // N*16 (bf16 pairs, layer 1)
    unsigned int* ABu2 = ABu + (size_t)N_NODES * 16;                // N*16 (layer 2)
    float* C    = (float*)(ABu2 + (size_t)N_NODES * 16);            // N*16 (p1)
    float* C2   = C + (size_t)N_NODES * 16;                         // N*16 (p2)
    int2*  EPB  = (int2*)(C2 + (size_t)N_NODES * 16);               // NBUCK*BCAP padded
    int* RANK   = (int*)(EPB + (size_t)NBUCK * BCAP);               // NBUCK
    int* ROWBEG = RANK + NBUCK;                                     // N
    int* ROWEND = ROWBEG + N_NODES;                                 // N

    const int* srcp = ei;
    const int* dstp = ei + N_EDGES;

    hipMemsetAsync(RANK, 0, NBUCK * sizeof(int), stream);

    k_node1<<<782, 256, 0, stream>>>(x, w1, root1, b1, ABu, C);
    k_part<<<PB_NB, 256, 0, stream>>>(srcp, dstp, ea, RANK, EPB);
    k_bsort<<<NBUCK, 256, 0, stream>>>(RANK, EPB, ROWBEG, ROWEND);
    k_gfused1<<<N_NODES / 4, 256, 0, stream>>>(ROWBEG, ROWEND, EPB, ABu, C,
                                               w2, root2, b2, ABu2, C2);
    k_gather2<<<N_NODES / 4, 256, 0, stream>>>(ROWBEG, ROWEND, EPB, ABu2, C2, out);
}